// Round 10
// baseline (935.648 us; speedup 1.0000x reference)
//
#include <hip/hip_runtime.h>

#define NN 40000
#define EE 512000
#define NSB 157  // (NN + 255) / 256

typedef unsigned short u16;

__device__ __forceinline__ float bf2f(u16 u) { return __uint_as_float(((unsigned)u) << 16); }
__device__ __forceinline__ u16 f2bf(float f) {
    unsigned u = __float_as_uint(f);
    u += 0x7FFFu + ((u >> 16) & 1u);
    return (u16)(u >> 16);
}
__device__ __forceinline__ float lrelu(float t) { return t > 0.f ? t : 0.2f * t; }

// ---------------- dtype detection ----------------
__global__ __launch_bounds__(256) void detect_k(const u16* __restrict__ x, int* __restrict__ flag) {
    int t = threadIdx.x;
    int cnt = 0;
    for (int j = 0; j < 8; ++j) {
        float v = bf2f(x[(t * 8 + j) * 2]);
        float a = fabsf(v);
        if (a >= 0.00390625f && a <= 256.0f) cnt++;
    }
    __shared__ int sh[256];
    sh[t] = cnt;
    __syncthreads();
    for (int off = 128; off > 0; off >>= 1) {
        if (t < off) sh[t] += sh[t + off];
        __syncthreads();
    }
    if (t == 0) flag[0] = (sh[0] > 1024) ? 1 : 0;
}

// ---------------- weight conversion ----------------
struct CvtArgs {
    const void* src[28];
    float* dst[28];
    int n[28];
};

__global__ __launch_bounds__(256) void cvt_k(CvtArgs a, const int* __restrict__ flag) {
    int b = blockIdx.x;
    int n = a.n[b];
    float* d = a.dst[b];
    if (*flag) {
        const u16* p = (const u16*)a.src[b];
        for (int i = threadIdx.x; i < n; i += 256) d[i] = bf2f(p[i]);
    } else {
        const float* p = (const float*)a.src[b];
        for (int i = threadIdx.x; i < n; i += 256) d[i] = p[i];
    }
}

// ---------------- CSR build ----------------
__global__ __launch_bounds__(256) void hist_k(const int* __restrict__ ei, int* __restrict__ cnt) {
    for (int e = blockIdx.x * 256 + threadIdx.x; e < EE; e += gridDim.x * 256) {
        int d = ei[EE + e];
        if ((unsigned)d < NN) atomicAdd(&cnt[d], 1);
    }
}

__global__ __launch_bounds__(256) void scan1_k(const int* __restrict__ cnt, int* __restrict__ rowptr,
                                               int* __restrict__ bsum) {
    int i = blockIdx.x * 256 + threadIdx.x;
    int v = (i < NN) ? cnt[i] : 0;
    __shared__ int sh[256];
    sh[threadIdx.x] = v;
    __syncthreads();
    for (int off = 1; off < 256; off <<= 1) {
        int t = (threadIdx.x >= off) ? sh[threadIdx.x - off] : 0;
        __syncthreads();
        sh[threadIdx.x] += t;
        __syncthreads();
    }
    if (i < NN) rowptr[i] = sh[threadIdx.x] - v;
    if (threadIdx.x == 255) bsum[blockIdx.x] = sh[255];
}

__global__ __launch_bounds__(256) void scan2_k(int* __restrict__ bsum, int* __restrict__ rowptr) {
    int tid = threadIdx.x;
    int v = (tid < NSB) ? bsum[tid] : 0;
    __shared__ int sh[256];
    sh[tid] = v;
    __syncthreads();
    for (int off = 1; off < 256; off <<= 1) {
        int t = (tid >= off) ? sh[tid - off] : 0;
        __syncthreads();
        sh[tid] += t;
        __syncthreads();
    }
    if (tid < NSB) bsum[tid] = sh[tid] - v;
    if (tid == 255) rowptr[NN] = sh[255];
}

__global__ __launch_bounds__(256) void scan3_k(int* __restrict__ rowptr, const int* __restrict__ bsum) {
    int i = blockIdx.x * 256 + threadIdx.x;
    if (i < NN) rowptr[i] += bsum[blockIdx.x];
}

__global__ __launch_bounds__(256) void scatter_k(const int* __restrict__ ei, const int* __restrict__ rowptr,
                                                 int* __restrict__ fill, int* __restrict__ csrc) {
    for (int e = blockIdx.x * 256 + threadIdx.x; e < EE; e += gridDim.x * 256) {
        int d = ei[EE + e];
        if ((unsigned)d >= NN) continue;
        int s = ei[e];
        if ((unsigned)s >= NN) s = 0;
        int p = rowptr[d] + atomicAdd(&fill[d], 1);
        csrc[p] = s;
    }
}

// ---------------- matmul + fused BN-of-previous-layer + fused es/ed epilogue ----------------
__global__ __launch_bounds__(256) void matmul128_k(const void* __restrict__ Xv, int mode,
                                                   const int* __restrict__ flag,
                                                   const float* __restrict__ bnacc,
                                                   const float* __restrict__ gam,
                                                   const float* __restrict__ bet,
                                                   const float* __restrict__ Wf,
                                                   const float* __restrict__ asf,
                                                   const float* __restrict__ adf,
                                                   u16* __restrict__ Yb,
                                                   float* __restrict__ es, float* __restrict__ ed) {
    __shared__ float Xs[64 * 128];
    __shared__ float scs[128], shs[128];
    int tid = threadIdx.x;
    size_t row0 = (size_t)blockIdx.x * 64;
    if (mode == 1) {
        if (tid < 128) {
            float mu = bnacc[tid] * (1.0f / NN);
            float var = bnacc[128 + tid] * (1.0f / NN) - mu * mu;
            float s = rsqrtf(var + 1e-5f) * gam[tid];
            scs[tid] = s;
            shs[tid] = bet[tid] - mu * s;
        }
        __syncthreads();
        const float4* X4 = reinterpret_cast<const float4*>((const float*)Xv + row0 * 128);
        for (int i = tid; i < 2048; i += 256) {
            float4 v = X4[i];
            int c0 = (i & 31) * 4;
            v.x = fmaf(v.x, scs[c0], shs[c0]);         v.x = v.x > 0.f ? v.x : 0.f;
            v.y = fmaf(v.y, scs[c0 + 1], shs[c0 + 1]); v.y = v.y > 0.f ? v.y : 0.f;
            v.z = fmaf(v.z, scs[c0 + 2], shs[c0 + 2]); v.z = v.z > 0.f ? v.z : 0.f;
            v.w = fmaf(v.w, scs[c0 + 3], shs[c0 + 3]); v.w = v.w > 0.f ? v.w : 0.f;
            *reinterpret_cast<float4*>(Xs + i * 4) = v;
        }
    } else if (*flag) {
        const uint2* X2 = reinterpret_cast<const uint2*>((const u16*)Xv + row0 * 128);
        for (int i = tid; i < 2048; i += 256) {
            uint2 p = X2[i];
            float4 v;
            v.x = bf2f((u16)(p.x & 0xffffu));
            v.y = bf2f((u16)(p.x >> 16));
            v.z = bf2f((u16)(p.y & 0xffffu));
            v.w = bf2f((u16)(p.y >> 16));
            *reinterpret_cast<float4*>(Xs + i * 4) = v;
        }
    } else {
        const float4* X4 = reinterpret_cast<const float4*>((const float*)Xv + row0 * 128);
        for (int i = tid; i < 2048; i += 256)
            *reinterpret_cast<float4*>(Xs + i * 4) = X4[i];
    }
    __syncthreads();
    int tx = tid & 31, ty = tid >> 5;
    float acc[8][4] = {};
    const float* Wp = Wf + tx * 4;
    for (int k = 0; k < 128; ++k) {
        float4 wv = *reinterpret_cast<const float4*>(Wp + (size_t)k * 128);
        const float* xr = Xs + k;
#pragma unroll
        for (int j = 0; j < 8; ++j) {
            float a = xr[(ty * 8 + j) * 128];
            acc[j][0] = fmaf(a, wv.x, acc[j][0]);
            acc[j][1] = fmaf(a, wv.y, acc[j][1]);
            acc[j][2] = fmaf(a, wv.z, acc[j][2]);
            acc[j][3] = fmaf(a, wv.w, acc[j][3]);
        }
    }
    u16* yp = Yb + (row0 + (size_t)ty * 8) * 128 + tx * 4;
#pragma unroll
    for (int j = 0; j < 8; ++j) {
        ushort4 v;
        v.x = f2bf(acc[j][0]); v.y = f2bf(acc[j][1]);
        v.z = f2bf(acc[j][2]); v.w = f2bf(acc[j][3]);
        *reinterpret_cast<ushort4*>(yp + j * 128) = v;
    }
    float a0 = asf[tx * 4], a1 = asf[tx * 4 + 1], a2 = asf[tx * 4 + 2], a3 = asf[tx * 4 + 3];
    float d0 = adf[tx * 4], d1 = adf[tx * 4 + 1], d2 = adf[tx * 4 + 2], d3 = adf[tx * 4 + 3];
    int hh = tx >> 3;
#pragma unroll
    for (int j = 0; j < 8; ++j) {
        float ps = acc[j][0] * a0 + acc[j][1] * a1 + acc[j][2] * a2 + acc[j][3] * a3;
        float pd = acc[j][0] * d0 + acc[j][1] * d1 + acc[j][2] * d2 + acc[j][3] * d3;
        ps += __shfl_xor(ps, 1, 64); pd += __shfl_xor(pd, 1, 64);
        ps += __shfl_xor(ps, 2, 64); pd += __shfl_xor(pd, 2, 64);
        ps += __shfl_xor(ps, 4, 64); pd += __shfl_xor(pd, 4, 64);
        if ((tx & 7) == 0) {
            size_t row = row0 + ty * 8 + j;
            es[row * 4 + hh] = ps;
            ed[row * 4 + hh] = pd;
        }
    }
}

// ---------------- GAT aggregation: one wave per destination node ----------------
// Softmax computed WITHOUT max-subtraction: scores = lrelu(es+ed) are O(10)
// (einsum of 32 ~N(0,1) products), exp stays far inside fp32 range, and softmax
// is shift-invariant so the result is identical to the reference up to rounding.
// This removes the entire phase-A max pass (one csrc+es gather per edge + reduce).
__global__ __launch_bounds__(256) void agg_k(const u16* __restrict__ hb, const float* __restrict__ es,
                                             const float* __restrict__ ed, const int* __restrict__ rowptr,
                                             const int* __restrict__ csrc, float* __restrict__ out) {
    int wid = (blockIdx.x * 256 + threadIdx.x) >> 6;
    int lane = threadIdx.x & 63;
    if (wid >= NN) return;
    int rs = rowptr[wid], re = rowptr[wid + 1];
    int deg = re - rs;
    int head = lane >> 4;
    float edn = ed[wid * 4 + head];
    float acc0, acc1, den;
    {
        float w = __expf(lrelu(es[wid * 4 + head] + edn));
        den = w;
        unsigned pv = ((const unsigned*)(hb + (size_t)wid * 128))[lane];
        acc0 = w * bf2f((u16)(pv & 0xffffu));
        acc1 = w * bf2f((u16)(pv >> 16));
    }
    int i = 0;
    for (; i + 8 <= deg; i += 8) {
        int sv[8];
#pragma unroll
        for (int j = 0; j < 8; ++j) sv[j] = csrc[rs + i + j];
        float wv[8];
#pragma unroll
        for (int j = 0; j < 8; ++j) wv[j] = __expf(lrelu(es[sv[j] * 4 + head] + edn));
        unsigned pv[8];
#pragma unroll
        for (int j = 0; j < 8; ++j) pv[j] = ((const unsigned*)(hb + (size_t)sv[j] * 128))[lane];
#pragma unroll
        for (int j = 0; j < 8; ++j) {
            den += wv[j];
            acc0 = fmaf(wv[j], bf2f((u16)(pv[j] & 0xffffu)), acc0);
            acc1 = fmaf(wv[j], bf2f((u16)(pv[j] >> 16)), acc1);
        }
    }
    for (; i < deg; ++i) {
        int s = csrc[rs + i];
        float w = __expf(lrelu(es[s * 4 + head] + edn));
        den += w;
        unsigned pv = ((const unsigned*)(hb + (size_t)s * 128))[lane];
        acc0 = fmaf(w, bf2f((u16)(pv & 0xffffu)), acc0);
        acc1 = fmaf(w, bf2f((u16)(pv >> 16)), acc1);
    }
    float inv = 1.0f / den;
    ((float2*)(out + (size_t)wid * 128))[lane] = make_float2(acc0 * inv, acc1 * inv);
}

// ---------------- BatchNorm stats over nodes ----------------
__global__ __launch_bounds__(256) void bn_stats_k(const float* __restrict__ x, float* __restrict__ accum) {
    int f = threadIdx.x & 127;
    int half = threadIdx.x >> 7;
    float s = 0.f, ss = 0.f;
    for (int r = blockIdx.x * 2 + half; r < NN; r += gridDim.x * 2) {
        float v = x[(size_t)r * 128 + f];
        s += v; ss += v * v;
    }
    __shared__ float ls[256], lss[256];
    ls[threadIdx.x] = s; lss[threadIdx.x] = ss;
    __syncthreads();
    if (threadIdx.x < 128) {
        atomicAdd(&accum[f], ls[threadIdx.x] + ls[threadIdx.x + 128]);
        atomicAdd(&accum[128 + f], lss[threadIdx.x] + lss[threadIdx.x + 128]);
    }
}

// ---------------- attention pooling ----------------
__global__ __launch_bounds__(256) void pool_score_k(const float* __restrict__ act,
                                                    const float* __restrict__ bnacc,
                                                    const float* __restrict__ gam,
                                                    const float* __restrict__ bet,
                                                    const float* __restrict__ attw,
                                                    float* __restrict__ sc) {
    int wid = (blockIdx.x * 256 + threadIdx.x) >> 6;
    int lane = threadIdx.x & 63;
    if (wid >= NN) return;
    float mu0 = bnacc[lane] * (1.0f / NN);
    float va0 = bnacc[128 + lane] * (1.0f / NN) - mu0 * mu0;
    float s0 = rsqrtf(va0 + 1e-5f) * gam[lane], b0 = bet[lane] - mu0 * s0;
    float mu1 = bnacc[64 + lane] * (1.0f / NN);
    float va1 = bnacc[192 + lane] * (1.0f / NN) - mu1 * mu1;
    float s1 = rsqrtf(va1 + 1e-5f) * gam[64 + lane], b1 = bet[64 + lane] - mu1 * s1;
    const float* a = act + (size_t)wid * 128;
    float v0 = fmaf(a[lane], s0, b0);      v0 = v0 > 0.f ? v0 : 0.f;
    float v1 = fmaf(a[64 + lane], s1, b1); v1 = v1 > 0.f ? v1 : 0.f;
    float v = v0 * attw[lane] + v1 * attw[64 + lane];
    for (int off = 1; off < 64; off <<= 1) v += __shfl_xor(v, off, 64);
    if (lane == 0) sc[wid] = v;
}

__device__ __forceinline__ int lower_bound_dev(const int* __restrict__ b, int n, int v) {
    int lo = 0, hi = n;
    while (lo < hi) {
        int mid = (lo + hi) >> 1;
        if (b[mid] < v) lo = mid + 1; else hi = mid;
    }
    return lo;
}

__global__ __launch_bounds__(256) void pool_stats_k(const float* __restrict__ sc, const int* __restrict__ batch,
                                                    float* __restrict__ md) {
    int g = blockIdx.x;
    int tid = threadIdx.x;
    int start = lower_bound_dev(batch, NN, g);
    int end = lower_bound_dev(batch, NN, g + 1);
    __shared__ float sh[256];
    float m = -3.0e38f;
    for (int i = start + tid; i < end; i += 256) m = fmaxf(m, sc[i]);
    sh[tid] = m; __syncthreads();
    for (int off = 128; off > 0; off >>= 1) {
        if (tid < off) sh[tid] = fmaxf(sh[tid], sh[tid + off]);
        __syncthreads();
    }
    m = sh[0]; __syncthreads();
    float dn = 0.f;
    for (int i = start + tid; i < end; i += 256) dn += __expf(sc[i] - m);
    sh[tid] = dn; __syncthreads();
    for (int off = 128; off > 0; off >>= 1) {
        if (tid < off) sh[tid] += sh[tid + off];
        __syncthreads();
    }
    if (tid == 0) {
        float den = sh[0];
        md[g * 2] = m;
        md[g * 2 + 1] = (den > 1e-30f) ? 1.0f / den : 0.0f;
    }
}

__global__ __launch_bounds__(256) void pool_accum2_k(const float* __restrict__ act, const float* __restrict__ sc,
                                                     const int* __restrict__ batch, const float* __restrict__ md,
                                                     const float* __restrict__ bnacc,
                                                     const float* __restrict__ gam,
                                                     const float* __restrict__ bet,
                                                     float* __restrict__ pooled) {
    int r0 = blockIdx.x * 64;
    int tid = threadIdx.x;
    __shared__ float wsh[64];
    __shared__ int gsh[64];
    if (tid < 64) {
        int g = batch[r0 + tid];
        if ((unsigned)g >= 64) g = 0;
        gsh[tid] = g;
        wsh[tid] = __expf(sc[r0 + tid] - md[g * 2]) * md[g * 2 + 1];
    }
    __syncthreads();
    int f = tid & 127, half = tid >> 7;
    float mu = bnacc[f] * (1.0f / NN);
    float va = bnacc[128 + f] * (1.0f / NN) - mu * mu;
    float bs = rsqrtf(va + 1e-5f) * gam[f], bb = bet[f] - mu * bs;
    float racc = 0.f;
    int curg = gsh[half];
    for (int r = half; r < 64; r += 2) {
        int g = gsh[r];
        if (g != curg) {
            atomicAdd(&pooled[curg * 128 + f], racc);
            racc = 0.f;
            curg = g;
        }
        float v = fmaf(act[(size_t)(r0 + r) * 128 + f], bs, bb);
        v = v > 0.f ? v : 0.f;
        racc = fmaf(wsh[r], v, racc);
    }
    atomicAdd(&pooled[curg * 128 + f], racc);
}

// ---------------- head A: per-graph fci matmul, LDS-staged ----------------
__global__ __launch_bounds__(256) void headA_k(const float* __restrict__ pooled,
                                               const float* __restrict__ fciw, const float* __restrict__ fcib,
                                               float* __restrict__ Tall) {
    __shared__ float Wl[6144];
    __shared__ float Pl[128];
    int tid = threadIdx.x;
    int g = blockIdx.x;
    for (int i = tid; i < 6144; i += 256) Wl[i] = fciw[i];
    if (tid < 128) Pl[tid] = pooled[g * 128 + tid];
    __syncthreads();
    if (tid < 48) {
        float s = fcib[tid];
        for (int k = 0; k < 128; ++k) s = fmaf(Pl[k], Wl[k * 48 + tid], s);
        Tall[g * 48 + tid] = s;
    }
}

// ---------------- head B: BN+fc per branch, concat, fc1+BN+fc2+sigmoid — all in LDS ----------------
__global__ __launch_bounds__(256) void headB_k(const float* __restrict__ Tall,
                                               const float* __restrict__ gbi, const float* __restrict__ bbi,
                                               const float* __restrict__ fcw, const float* __restrict__ fcb,
                                               const float* __restrict__ fc1w, const float* __restrict__ fc1b,
                                               const float* __restrict__ gf1, const float* __restrict__ bf1,
                                               const float* __restrict__ fc2w, const float* __restrict__ fc2b,
                                               void* __restrict__ out, const int* __restrict__ flag) {
    __shared__ float T[6144];
    __shared__ float X[64 * 24];
    __shared__ float Y[64 * 12];
    __shared__ float st[192];
    __shared__ float st2[24];
    __shared__ float wl[576 + 288 + 12 + 12 + 12 + 12 + 48 + 48 + 1];
    float* fcw_l  = wl;
    float* fc1w_l = wl + 576;
    float* fcb_l  = wl + 864;
    float* fc1b_l = wl + 876;
    float* gf1_l  = wl + 888;
    float* bf1_l  = wl + 900;
    float* gbi_l  = wl + 912;
    float* bbi_l  = wl + 960;
    float* fc2b_l = wl + 1008;
    __shared__ float fc2w_l[12];
    int tid = threadIdx.x;
    for (int i = tid; i < 6144; i += 256) T[i] = Tall[i];
    for (int i = tid; i < 576; i += 256) fcw_l[i] = fcw[i];
    for (int i = tid; i < 288; i += 256) fc1w_l[i] = fc1w[i];
    if (tid < 12) {
        fcb_l[tid] = fcb[tid]; fc1b_l[tid] = fc1b[tid];
        gf1_l[tid] = gf1[tid]; bf1_l[tid] = bf1[tid];
        fc2w_l[tid] = fc2w[tid];
    }
    if (tid < 48) { gbi_l[tid] = gbi[tid]; bbi_l[tid] = bbi[tid]; }
    if (tid == 0) fc2b_l[0] = fc2b[0];
    __syncthreads();
    if (tid < 96) {
        int b = tid / 48, c = tid - b * 48;
        float s = 0.f, ss = 0.f;
        for (int g = 0; g < 64; ++g) { float v = T[b * 3072 + g * 48 + c]; s += v; ss += v * v; }
        float mu = s * (1.f / 64), var = ss * (1.f / 64) - mu * mu;
        float sc_ = rsqrtf(var + 1e-5f) * gbi_l[c];
        st[tid] = sc_;
        st[96 + tid] = bbi_l[c] - mu * sc_;
    }
    __syncthreads();
    for (int i = tid; i < 6144; i += 256) {
        int b = i / 3072, c = i % 48;
        int col = b * 48 + c;
        float v = fmaf(T[i], st[col], st[96 + col]);
        T[i] = v > 0.f ? v : 0.f;
    }
    __syncthreads();
    for (int idx = tid; idx < 1536; idx += 256) {
        int b = idx / 768, r = idx - b * 768;
        int g = r / 12, c = r - g * 12;
        float s = fcb_l[c];
        const float* tr = T + b * 3072 + g * 48;
        for (int k = 0; k < 48; ++k) s = fmaf(tr[k], fcw_l[k * 12 + c], s);
        X[g * 24 + b * 12 + c] = s;
    }
    __syncthreads();
    for (int idx = tid; idx < 768; idx += 256) {
        int g = idx / 12, c = idx - g * 12;
        float s = fc1b_l[c];
        const float* xr = X + g * 24;
        for (int k = 0; k < 24; ++k) s = fmaf(xr[k], fc1w_l[k * 12 + c], s);
        Y[idx] = s;
    }
    __syncthreads();
    if (tid < 12) {
        float s = 0.f, ss = 0.f;
        for (int g = 0; g < 64; ++g) { float v = Y[g * 12 + tid]; s += v; ss += v * v; }
        float mu = s * (1.f / 64), var = ss * (1.f / 64) - mu * mu;
        float sc_ = rsqrtf(var + 1e-5f) * gf1_l[tid];
        st2[tid] = sc_;
        st2[12 + tid] = bf1_l[tid] - mu * sc_;
    }
    __syncthreads();
    if (tid < 64) {
        float s = fc2b_l[0];
        for (int k = 0; k < 12; ++k) {
            float v = fmaf(Y[tid * 12 + k], st2[k], st2[12 + k]);
            v = v > 0.f ? v : 0.f;
            s = fmaf(v, fc2w_l[k], s);
        }
        float sig = 1.f / (1.f + __expf(-s));
        if (*flag) ((u16*)out)[tid] = f2bf(sig);
        else       ((float*)out)[tid] = sig;
    }
}

extern "C" void kernel_launch(void* const* d_in, const int* in_sizes, int n_in,
                              void* d_out, int out_size, void* d_ws, size_t ws_size,
                              hipStream_t stream) {
    const void* xin[2]  = {d_in[0], d_in[1]};
    const int* ei[2]    = {(const int*)d_in[2], (const int*)d_in[3]};
    const int* batch[2] = {(const int*)d_in[4], (const int*)d_in[5]};

    // ---- workspace layout (total ~35.0 MB) ----
    char* ws = (char*)d_ws;
    u16*   Hb     = (u16*)(ws + 0);              // 10,240,000
    float* A      = (float*)(ws + 10240000);     // 20,480,000
    float* es     = (float*)(ws + 30720000);     //    640,000
    float* ed     = (float*)(ws + 31360000);     //    640,000
    float* sc     = (float*)(ws + 32000000);     //    160,000
    int*   cnt    = (int*)(ws + 32160000);       //    160,000
    int*   fill   = (int*)(ws + 32320000);       //    160,000 (adjacent to cnt)
    int*   rowptr = (int*)(ws + 32480000);       //    160,016
    int*   csrc   = (int*)(ws + 32640016);       //  2,048,000
    float* wcvt   = (float*)(ws + 34688016);     //    240,000
    float* zbase  = (float*)(ws + 34928016);
    float* bn_accum = zbase;                     //  6*256
    float* pooled   = zbase + 1536;              //  2*8192
    float* md       = pooled + 16384;            //  2*128
    float* Tall     = md + 256;                  //  2*64*48 = 6144
    int*   flag     = (int*)(Tall + 6144);       //  1
    int*   bsum     = flag + 4;                  //  NSB

    // ---- weight conversion table ----
    static const int widx[28] = {6,7,8, 10,11,12, 14,15,16, 18,19,20, 23,24,25,
                                 21,26, 22,27, 28, 30,31, 32,33, 34,35, 36,37};
    static const int wn[28]   = {16384,128,128, 16384,128,128, 16384,128,128, 128,128,128,
                                 128,128,128, 48,48, 12,12, 128, 6144,48, 576,12, 288,12, 12,1};
    CvtArgs ca;
    float* wptr[28];
    {
        size_t off = 0;
        for (int i = 0; i < 28; ++i) {
            ca.src[i] = d_in[widx[i]];
            ca.dst[i] = wcvt + off;
            ca.n[i] = wn[i];
            wptr[i] = wcvt + off;
            off += wn[i];
        }
    }
    const float* Wf[3]  = {wptr[0], wptr[3], wptr[6]};
    const float* asf[3] = {wptr[1], wptr[4], wptr[7]};
    const float* adf[3] = {wptr[2], wptr[5], wptr[8]};
    const float* gf[3]  = {wptr[9], wptr[10], wptr[11]};
    const float* bef[3] = {wptr[12], wptr[13], wptr[14]};
    const float *gbi = wptr[15], *bbi = wptr[16], *gf1 = wptr[17], *bf1 = wptr[18];
    const float *attw = wptr[19], *fciw = wptr[20], *fcib = wptr[21];
    const float *fcw = wptr[22], *fcb = wptr[23], *fc1w = wptr[24], *fc1b = wptr[25];
    const float *fc2w = wptr[26], *fc2b = wptr[27];

    detect_k<<<1, 256, 0, stream>>>((const u16*)d_in[0], flag);
    cvt_k<<<28, 256, 0, stream>>>(ca, flag);
    (void)hipMemsetAsync(zbase, 0, (1536 + 16384) * sizeof(float), stream);  // bn_accum + pooled

    for (int b = 0; b < 2; ++b) {
        (void)hipMemsetAsync(cnt, 0, 2 * NN * sizeof(int), stream);  // cnt + fill
        hist_k<<<512, 256, 0, stream>>>(ei[b], cnt);
        scan1_k<<<NSB, 256, 0, stream>>>(cnt, rowptr, bsum);
        scan2_k<<<1, 256, 0, stream>>>(bsum, rowptr);
        scan3_k<<<NSB, 256, 0, stream>>>(rowptr, bsum);
        scatter_k<<<512, 256, 0, stream>>>(ei[b], rowptr, fill, csrc);
        for (int l = 0; l < 3; ++l) {
            float* accp = bn_accum + (b * 3 + l) * 256;
            float* accprev = bn_accum + (b * 3 + l - 1) * 256;  // only read when l>0
            matmul128_k<<<625, 256, 0, stream>>>(l == 0 ? xin[b] : (const void*)A,
                                                 l == 0 ? 0 : 1, flag,
                                                 l == 0 ? bn_accum : accprev,
                                                 l == 0 ? gf[0] : gf[l - 1],
                                                 l == 0 ? bef[0] : bef[l - 1],
                                                 Wf[l], asf[l], adf[l], Hb, es, ed);
            agg_k<<<10000, 256, 0, stream>>>(Hb, es, ed, rowptr, csrc, A);
            bn_stats_k<<<1024, 256, 0, stream>>>(A, accp);
        }
        float* acc3 = bn_accum + (b * 3 + 2) * 256;
        pool_score_k<<<10000, 256, 0, stream>>>(A, acc3, gf[2], bef[2], attw, sc);
        pool_stats_k<<<64, 256, 0, stream>>>(sc, batch[b], md + b * 128);
        pool_accum2_k<<<625, 256, 0, stream>>>(A, sc, batch[b], md + b * 128,
                                               acc3, gf[2], bef[2], pooled + b * 8192);
        headA_k<<<64, 256, 0, stream>>>(pooled + b * 8192, fciw, fcib, Tall + b * 3072);
    }
    headB_k<<<1, 256, 0, stream>>>(Tall, gbi, bbi, fcw, fcb, fc1w, fc1b, gf1, bf1,
                                   fc2w, fc2b, d_out, flag);
}

// Round 11
// 786.385 us; speedup vs baseline: 1.1898x; 1.1898x over previous
//
#include <hip/hip_runtime.h>

#define NN 40000
#define EE 512000
#define NSB 157  // (NN + 255) / 256

typedef unsigned short u16;

__device__ __forceinline__ float bf2f(u16 u) { return __uint_as_float(((unsigned)u) << 16); }
__device__ __forceinline__ u16 f2bf(float f) {
    unsigned u = __float_as_uint(f);
    u += 0x7FFFu + ((u >> 16) & 1u);
    return (u16)(u >> 16);
}
__device__ __forceinline__ float lrelu(float t) { return t > 0.f ? t : 0.2f * t; }

// ---------------- dtype detection ----------------
__global__ __launch_bounds__(256) void detect_k(const u16* __restrict__ x, int* __restrict__ flag) {
    int t = threadIdx.x;
    int cnt = 0;
    for (int j = 0; j < 8; ++j) {
        float v = bf2f(x[(t * 8 + j) * 2]);
        float a = fabsf(v);
        if (a >= 0.00390625f && a <= 256.0f) cnt++;
    }
    __shared__ int sh[256];
    sh[t] = cnt;
    __syncthreads();
    for (int off = 128; off > 0; off >>= 1) {
        if (t < off) sh[t] += sh[t + off];
        __syncthreads();
    }
    if (t == 0) flag[0] = (sh[0] > 1024) ? 1 : 0;
}

// ---------------- weight conversion ----------------
struct CvtArgs {
    const void* src[28];
    float* dst[28];
    int n[28];
};

__global__ __launch_bounds__(256) void cvt_k(CvtArgs a, const int* __restrict__ flag) {
    int b = blockIdx.x;
    int n = a.n[b];
    float* d = a.dst[b];
    if (*flag) {
        const u16* p = (const u16*)a.src[b];
        for (int i = threadIdx.x; i < n; i += 256) d[i] = bf2f(p[i]);
    } else {
        const float* p = (const float*)a.src[b];
        for (int i = threadIdx.x; i < n; i += 256) d[i] = p[i];
    }
}

// ---------------- CSR build ----------------
__global__ __launch_bounds__(256) void hist_k(const int* __restrict__ ei, int* __restrict__ cnt) {
    for (int e = blockIdx.x * 256 + threadIdx.x; e < EE; e += gridDim.x * 256) {
        int d = ei[EE + e];
        if ((unsigned)d < NN) atomicAdd(&cnt[d], 1);
    }
}

__global__ __launch_bounds__(256) void scan1_k(const int* __restrict__ cnt, int* __restrict__ rowptr,
                                               int* __restrict__ bsum) {
    int i = blockIdx.x * 256 + threadIdx.x;
    int v = (i < NN) ? cnt[i] : 0;
    __shared__ int sh[256];
    sh[threadIdx.x] = v;
    __syncthreads();
    for (int off = 1; off < 256; off <<= 1) {
        int t = (threadIdx.x >= off) ? sh[threadIdx.x - off] : 0;
        __syncthreads();
        sh[threadIdx.x] += t;
        __syncthreads();
    }
    if (i < NN) rowptr[i] = sh[threadIdx.x] - v;
    if (threadIdx.x == 255) bsum[blockIdx.x] = sh[255];
}

__global__ __launch_bounds__(256) void scan2_k(int* __restrict__ bsum, int* __restrict__ rowptr) {
    int tid = threadIdx.x;
    int v = (tid < NSB) ? bsum[tid] : 0;
    __shared__ int sh[256];
    sh[tid] = v;
    __syncthreads();
    for (int off = 1; off < 256; off <<= 1) {
        int t = (tid >= off) ? sh[tid - off] : 0;
        __syncthreads();
        sh[tid] += t;
        __syncthreads();
    }
    if (tid < NSB) bsum[tid] = sh[tid] - v;
    if (tid == 255) rowptr[NN] = sh[255];
}

__global__ __launch_bounds__(256) void scan3_k(int* __restrict__ rowptr, const int* __restrict__ bsum) {
    int i = blockIdx.x * 256 + threadIdx.x;
    if (i < NN) rowptr[i] += bsum[blockIdx.x];
}

__global__ __launch_bounds__(256) void scatter_k(const int* __restrict__ ei, const int* __restrict__ rowptr,
                                                 int* __restrict__ fill, int* __restrict__ csrc) {
    for (int e = blockIdx.x * 256 + threadIdx.x; e < EE; e += gridDim.x * 256) {
        int d = ei[EE + e];
        if ((unsigned)d >= NN) continue;
        int s = ei[e];
        if ((unsigned)s >= NN) s = 0;
        int p = rowptr[d] + atomicAdd(&fill[d], 1);
        csrc[p] = s;
    }
}

// ---------------- matmul + fused BN-of-previous-layer + fused es/ed epilogue ----------------
__global__ __launch_bounds__(256) void matmul128_k(const void* __restrict__ Xv, int mode,
                                                   const int* __restrict__ flag,
                                                   const float* __restrict__ bnacc,
                                                   const float* __restrict__ gam,
                                                   const float* __restrict__ bet,
                                                   const float* __restrict__ Wf,
                                                   const float* __restrict__ asf,
                                                   const float* __restrict__ adf,
                                                   u16* __restrict__ Yb,
                                                   float* __restrict__ es, float* __restrict__ ed) {
    __shared__ float Xs[64 * 128];
    __shared__ float scs[128], shs[128];
    int tid = threadIdx.x;
    size_t row0 = (size_t)blockIdx.x * 64;
    if (mode == 1) {
        if (tid < 128) {
            float mu = bnacc[tid] * (1.0f / NN);
            float var = bnacc[128 + tid] * (1.0f / NN) - mu * mu;
            float s = rsqrtf(var + 1e-5f) * gam[tid];
            scs[tid] = s;
            shs[tid] = bet[tid] - mu * s;
        }
        __syncthreads();
        const float4* X4 = reinterpret_cast<const float4*>((const float*)Xv + row0 * 128);
        for (int i = tid; i < 2048; i += 256) {
            float4 v = X4[i];
            int c0 = (i & 31) * 4;
            v.x = fmaf(v.x, scs[c0], shs[c0]);         v.x = v.x > 0.f ? v.x : 0.f;
            v.y = fmaf(v.y, scs[c0 + 1], shs[c0 + 1]); v.y = v.y > 0.f ? v.y : 0.f;
            v.z = fmaf(v.z, scs[c0 + 2], shs[c0 + 2]); v.z = v.z > 0.f ? v.z : 0.f;
            v.w = fmaf(v.w, scs[c0 + 3], shs[c0 + 3]); v.w = v.w > 0.f ? v.w : 0.f;
            *reinterpret_cast<float4*>(Xs + i * 4) = v;
        }
    } else if (*flag) {
        const uint2* X2 = reinterpret_cast<const uint2*>((const u16*)Xv + row0 * 128);
        for (int i = tid; i < 2048; i += 256) {
            uint2 p = X2[i];
            float4 v;
            v.x = bf2f((u16)(p.x & 0xffffu));
            v.y = bf2f((u16)(p.x >> 16));
            v.z = bf2f((u16)(p.y & 0xffffu));
            v.w = bf2f((u16)(p.y >> 16));
            *reinterpret_cast<float4*>(Xs + i * 4) = v;
        }
    } else {
        const float4* X4 = reinterpret_cast<const float4*>((const float*)Xv + row0 * 128);
        for (int i = tid; i < 2048; i += 256)
            *reinterpret_cast<float4*>(Xs + i * 4) = X4[i];
    }
    __syncthreads();
    int tx = tid & 31, ty = tid >> 5;
    float acc[8][4] = {};
    const float* Wp = Wf + tx * 4;
    for (int k = 0; k < 128; ++k) {
        float4 wv = *reinterpret_cast<const float4*>(Wp + (size_t)k * 128);
        const float* xr = Xs + k;
#pragma unroll
        for (int j = 0; j < 8; ++j) {
            float a = xr[(ty * 8 + j) * 128];
            acc[j][0] = fmaf(a, wv.x, acc[j][0]);
            acc[j][1] = fmaf(a, wv.y, acc[j][1]);
            acc[j][2] = fmaf(a, wv.z, acc[j][2]);
            acc[j][3] = fmaf(a, wv.w, acc[j][3]);
        }
    }
    u16* yp = Yb + (row0 + (size_t)ty * 8) * 128 + tx * 4;
#pragma unroll
    for (int j = 0; j < 8; ++j) {
        ushort4 v;
        v.x = f2bf(acc[j][0]); v.y = f2bf(acc[j][1]);
        v.z = f2bf(acc[j][2]); v.w = f2bf(acc[j][3]);
        *reinterpret_cast<ushort4*>(yp + j * 128) = v;
    }
    float a0 = asf[tx * 4], a1 = asf[tx * 4 + 1], a2 = asf[tx * 4 + 2], a3 = asf[tx * 4 + 3];
    float d0 = adf[tx * 4], d1 = adf[tx * 4 + 1], d2 = adf[tx * 4 + 2], d3 = adf[tx * 4 + 3];
    int hh = tx >> 3;
#pragma unroll
    for (int j = 0; j < 8; ++j) {
        float ps = acc[j][0] * a0 + acc[j][1] * a1 + acc[j][2] * a2 + acc[j][3] * a3;
        float pd = acc[j][0] * d0 + acc[j][1] * d1 + acc[j][2] * d2 + acc[j][3] * d3;
        ps += __shfl_xor(ps, 1, 64); pd += __shfl_xor(pd, 1, 64);
        ps += __shfl_xor(ps, 2, 64); pd += __shfl_xor(pd, 2, 64);
        ps += __shfl_xor(ps, 4, 64); pd += __shfl_xor(pd, 4, 64);
        if ((tx & 7) == 0) {
            size_t row = row0 + ty * 8 + j;
            es[row * 4 + hh] = ps;
            ed[row * 4 + hh] = pd;
        }
    }
}

// ---------------- GAT aggregation + fused BN-stat accumulation ----------------
// No max-subtraction (softmax shift-invariant; scores O(10), exp far from overflow).
// Epilogue: 4-wave LDS reduce of (sum, sumsq) over the block's 4 nodes, then one
// 256-float atomicAdd flush into a 64-bucket spread array (~156 adds/address).
__global__ __launch_bounds__(256) void agg_k(const u16* __restrict__ hb, const float* __restrict__ es,
                                             const float* __restrict__ ed, const int* __restrict__ rowptr,
                                             const int* __restrict__ csrc, float* __restrict__ out,
                                             float* __restrict__ bkt) {
    __shared__ float ss[512], qq[512];
    int wid = (blockIdx.x * 256 + threadIdx.x) >> 6;
    int lane = threadIdx.x & 63;
    // NN = 40000 = 10000 blocks * 4 waves: every wave is active (no early return).
    int rs = rowptr[wid], re = rowptr[wid + 1];
    int deg = re - rs;
    int head = lane >> 4;
    float edn = ed[wid * 4 + head];
    float acc0, acc1, den;
    {
        float w = __expf(lrelu(es[wid * 4 + head] + edn));
        den = w;
        unsigned pv = ((const unsigned*)(hb + (size_t)wid * 128))[lane];
        acc0 = w * bf2f((u16)(pv & 0xffffu));
        acc1 = w * bf2f((u16)(pv >> 16));
    }
    int i = 0;
    for (; i + 8 <= deg; i += 8) {
        int sv[8];
#pragma unroll
        for (int j = 0; j < 8; ++j) sv[j] = csrc[rs + i + j];
        float wv[8];
#pragma unroll
        for (int j = 0; j < 8; ++j) wv[j] = __expf(lrelu(es[sv[j] * 4 + head] + edn));
        unsigned pv[8];
#pragma unroll
        for (int j = 0; j < 8; ++j) pv[j] = ((const unsigned*)(hb + (size_t)sv[j] * 128))[lane];
#pragma unroll
        for (int j = 0; j < 8; ++j) {
            den += wv[j];
            acc0 = fmaf(wv[j], bf2f((u16)(pv[j] & 0xffffu)), acc0);
            acc1 = fmaf(wv[j], bf2f((u16)(pv[j] >> 16)), acc1);
        }
    }
    for (; i < deg; ++i) {
        int s = csrc[rs + i];
        float w = __expf(lrelu(es[s * 4 + head] + edn));
        den += w;
        unsigned pv = ((const unsigned*)(hb + (size_t)s * 128))[lane];
        acc0 = fmaf(w, bf2f((u16)(pv & 0xffffu)), acc0);
        acc1 = fmaf(w, bf2f((u16)(pv >> 16)), acc1);
    }
    float inv = 1.0f / den;
    float v0 = acc0 * inv, v1 = acc1 * inv;
    ((float2*)(out + (size_t)wid * 128))[lane] = make_float2(v0, v1);
    // fused BN stats
    int w = threadIdx.x >> 6;
    ss[w * 128 + 2 * lane] = v0;     ss[w * 128 + 2 * lane + 1] = v1;
    qq[w * 128 + 2 * lane] = v0 * v0; qq[w * 128 + 2 * lane + 1] = v1 * v1;
    __syncthreads();
    int t = threadIdx.x;
    float* dst = bkt + (blockIdx.x & 63) * 256;
    if (t < 128) {
        atomicAdd(&dst[t], ss[t] + ss[128 + t] + ss[256 + t] + ss[384 + t]);
    } else {
        int f = t - 128;
        atomicAdd(&dst[t], qq[f] + qq[128 + f] + qq[256 + f] + qq[384 + f]);
    }
}

// fold 64 buckets -> bn_accum[256], and re-zero buckets for the next layer
__global__ __launch_bounds__(256) void bnreduce_k(float* __restrict__ bkt, float* __restrict__ accum) {
    int t = threadIdx.x;
    float s = 0.f;
    for (int b = 0; b < 64; ++b) {
        s += bkt[b * 256 + t];
        bkt[b * 256 + t] = 0.f;
    }
    accum[t] = s;
}

// ---------------- attention pooling ----------------
__global__ __launch_bounds__(256) void pool_score_k(const float* __restrict__ act,
                                                    const float* __restrict__ bnacc,
                                                    const float* __restrict__ gam,
                                                    const float* __restrict__ bet,
                                                    const float* __restrict__ attw,
                                                    float* __restrict__ sc) {
    int wid = (blockIdx.x * 256 + threadIdx.x) >> 6;
    int lane = threadIdx.x & 63;
    if (wid >= NN) return;
    float mu0 = bnacc[lane] * (1.0f / NN);
    float va0 = bnacc[128 + lane] * (1.0f / NN) - mu0 * mu0;
    float s0 = rsqrtf(va0 + 1e-5f) * gam[lane], b0 = bet[lane] - mu0 * s0;
    float mu1 = bnacc[64 + lane] * (1.0f / NN);
    float va1 = bnacc[192 + lane] * (1.0f / NN) - mu1 * mu1;
    float s1 = rsqrtf(va1 + 1e-5f) * gam[64 + lane], b1 = bet[64 + lane] - mu1 * s1;
    const float* a = act + (size_t)wid * 128;
    float v0 = fmaf(a[lane], s0, b0);      v0 = v0 > 0.f ? v0 : 0.f;
    float v1 = fmaf(a[64 + lane], s1, b1); v1 = v1 > 0.f ? v1 : 0.f;
    float v = v0 * attw[lane] + v1 * attw[64 + lane];
    for (int off = 1; off < 64; off <<= 1) v += __shfl_xor(v, off, 64);
    if (lane == 0) sc[wid] = v;
}

__device__ __forceinline__ int lower_bound_dev(const int* __restrict__ b, int n, int v) {
    int lo = 0, hi = n;
    while (lo < hi) {
        int mid = (lo + hi) >> 1;
        if (b[mid] < v) lo = mid + 1; else hi = mid;
    }
    return lo;
}

__global__ __launch_bounds__(256) void pool_stats_k(const float* __restrict__ sc, const int* __restrict__ batch,
                                                    float* __restrict__ md) {
    int g = blockIdx.x;
    int tid = threadIdx.x;
    int start = lower_bound_dev(batch, NN, g);
    int end = lower_bound_dev(batch, NN, g + 1);
    __shared__ float sh[256];
    float m = -3.0e38f;
    for (int i = start + tid; i < end; i += 256) m = fmaxf(m, sc[i]);
    sh[tid] = m; __syncthreads();
    for (int off = 128; off > 0; off >>= 1) {
        if (tid < off) sh[tid] = fmaxf(sh[tid], sh[tid + off]);
        __syncthreads();
    }
    m = sh[0]; __syncthreads();
    float dn = 0.f;
    for (int i = start + tid; i < end; i += 256) dn += __expf(sc[i] - m);
    sh[tid] = dn; __syncthreads();
    for (int off = 128; off > 0; off >>= 1) {
        if (tid < off) sh[tid] += sh[tid + off];
        __syncthreads();
    }
    if (tid == 0) {
        float den = sh[0];
        md[g * 2] = m;
        md[g * 2 + 1] = (den > 1e-30f) ? 1.0f / den : 0.0f;
    }
}

__global__ __launch_bounds__(256) void pool_accum2_k(const float* __restrict__ act, const float* __restrict__ sc,
                                                     const int* __restrict__ batch, const float* __restrict__ md,
                                                     const float* __restrict__ bnacc,
                                                     const float* __restrict__ gam,
                                                     const float* __restrict__ bet,
                                                     float* __restrict__ pooled) {
    int r0 = blockIdx.x * 64;
    int tid = threadIdx.x;
    __shared__ float wsh[64];
    __shared__ int gsh[64];
    if (tid < 64) {
        int g = batch[r0 + tid];
        if ((unsigned)g >= 64) g = 0;
        gsh[tid] = g;
        wsh[tid] = __expf(sc[r0 + tid] - md[g * 2]) * md[g * 2 + 1];
    }
    __syncthreads();
    int f = tid & 127, half = tid >> 7;
    float mu = bnacc[f] * (1.0f / NN);
    float va = bnacc[128 + f] * (1.0f / NN) - mu * mu;
    float bs = rsqrtf(va + 1e-5f) * gam[f], bb = bet[f] - mu * bs;
    float racc = 0.f;
    int curg = gsh[half];
    for (int r = half; r < 64; r += 2) {
        int g = gsh[r];
        if (g != curg) {
            atomicAdd(&pooled[curg * 128 + f], racc);
            racc = 0.f;
            curg = g;
        }
        float v = fmaf(act[(size_t)(r0 + r) * 128 + f], bs, bb);
        v = v > 0.f ? v : 0.f;
        racc = fmaf(wsh[r], v, racc);
    }
    atomicAdd(&pooled[curg * 128 + f], racc);
}

// ---------------- head A ----------------
__global__ __launch_bounds__(256) void headA_k(const float* __restrict__ pooled,
                                               const float* __restrict__ fciw, const float* __restrict__ fcib,
                                               float* __restrict__ Tall) {
    __shared__ float Wl[6144];
    __shared__ float Pl[128];
    int tid = threadIdx.x;
    int g = blockIdx.x;
    for (int i = tid; i < 6144; i += 256) Wl[i] = fciw[i];
    if (tid < 128) Pl[tid] = pooled[g * 128 + tid];
    __syncthreads();
    if (tid < 48) {
        float s = fcib[tid];
        for (int k = 0; k < 128; ++k) s = fmaf(Pl[k], Wl[k * 48 + tid], s);
        Tall[g * 48 + tid] = s;
    }
}

// ---------------- head B ----------------
__global__ __launch_bounds__(256) void headB_k(const float* __restrict__ Tall,
                                               const float* __restrict__ gbi, const float* __restrict__ bbi,
                                               const float* __restrict__ fcw, const float* __restrict__ fcb,
                                               const float* __restrict__ fc1w, const float* __restrict__ fc1b,
                                               const float* __restrict__ gf1, const float* __restrict__ bf1,
                                               const float* __restrict__ fc2w, const float* __restrict__ fc2b,
                                               void* __restrict__ out, const int* __restrict__ flag) {
    __shared__ float T[6144];
    __shared__ float X[64 * 24];
    __shared__ float Y[64 * 12];
    __shared__ float st[192];
    __shared__ float st2[24];
    __shared__ float wl[576 + 288 + 12 + 12 + 12 + 12 + 48 + 48 + 1];
    float* fcw_l  = wl;
    float* fc1w_l = wl + 576;
    float* fcb_l  = wl + 864;
    float* fc1b_l = wl + 876;
    float* gf1_l  = wl + 888;
    float* bf1_l  = wl + 900;
    float* gbi_l  = wl + 912;
    float* bbi_l  = wl + 960;
    float* fc2b_l = wl + 1008;
    __shared__ float fc2w_l[12];
    int tid = threadIdx.x;
    for (int i = tid; i < 6144; i += 256) T[i] = Tall[i];
    for (int i = tid; i < 576; i += 256) fcw_l[i] = fcw[i];
    for (int i = tid; i < 288; i += 256) fc1w_l[i] = fc1w[i];
    if (tid < 12) {
        fcb_l[tid] = fcb[tid]; fc1b_l[tid] = fc1b[tid];
        gf1_l[tid] = gf1[tid]; bf1_l[tid] = bf1[tid];
        fc2w_l[tid] = fc2w[tid];
    }
    if (tid < 48) { gbi_l[tid] = gbi[tid]; bbi_l[tid] = bbi[tid]; }
    if (tid == 0) fc2b_l[0] = fc2b[0];
    __syncthreads();
    if (tid < 96) {
        int b = tid / 48, c = tid - b * 48;
        float s = 0.f, ss = 0.f;
        for (int g = 0; g < 64; ++g) { float v = T[b * 3072 + g * 48 + c]; s += v; ss += v * v; }
        float mu = s * (1.f / 64), var = ss * (1.f / 64) - mu * mu;
        float sc_ = rsqrtf(var + 1e-5f) * gbi_l[c];
        st[tid] = sc_;
        st[96 + tid] = bbi_l[c] - mu * sc_;
    }
    __syncthreads();
    for (int i = tid; i < 6144; i += 256) {
        int b = i / 3072, c = i % 48;
        int col = b * 48 + c;
        float v = fmaf(T[i], st[col], st[96 + col]);
        T[i] = v > 0.f ? v : 0.f;
    }
    __syncthreads();
    for (int idx = tid; idx < 1536; idx += 256) {
        int b = idx / 768, r = idx - b * 768;
        int g = r / 12, c = r - g * 12;
        float s = fcb_l[c];
        const float* tr = T + b * 3072 + g * 48;
        for (int k = 0; k < 48; ++k) s = fmaf(tr[k], fcw_l[k * 12 + c], s);
        X[g * 24 + b * 12 + c] = s;
    }
    __syncthreads();
    for (int idx = tid; idx < 768; idx += 256) {
        int g = idx / 12, c = idx - g * 12;
        float s = fc1b_l[c];
        const float* xr = X + g * 24;
        for (int k = 0; k < 24; ++k) s = fmaf(xr[k], fc1w_l[k * 12 + c], s);
        Y[idx] = s;
    }
    __syncthreads();
    if (tid < 12) {
        float s = 0.f, ss = 0.f;
        for (int g = 0; g < 64; ++g) { float v = Y[g * 12 + tid]; s += v; ss += v * v; }
        float mu = s * (1.f / 64), var = ss * (1.f / 64) - mu * mu;
        float sc_ = rsqrtf(var + 1e-5f) * gf1_l[tid];
        st2[tid] = sc_;
        st2[12 + tid] = bf1_l[tid] - mu * sc_;
    }
    __syncthreads();
    if (tid < 64) {
        float s = fc2b_l[0];
        for (int k = 0; k < 12; ++k) {
            float v = fmaf(Y[tid * 12 + k], st2[k], st2[12 + k]);
            v = v > 0.f ? v : 0.f;
            s = fmaf(v, fc2w_l[k], s);
        }
        float sig = 1.f / (1.f + __expf(-s));
        if (*flag) ((u16*)out)[tid] = f2bf(sig);
        else       ((float*)out)[tid] = sig;
    }
}

extern "C" void kernel_launch(void* const* d_in, const int* in_sizes, int n_in,
                              void* d_out, int out_size, void* d_ws, size_t ws_size,
                              hipStream_t stream) {
    const void* xin[2]  = {d_in[0], d_in[1]};
    const int* ei[2]    = {(const int*)d_in[2], (const int*)d_in[3]};
    const int* batch[2] = {(const int*)d_in[4], (const int*)d_in[5]};

    // ---- workspace layout ----
    char* ws = (char*)d_ws;
    u16*   Hb     = (u16*)(ws + 0);              // 10,240,000
    float* A      = (float*)(ws + 10240000);     // 20,480,000
    float* es     = (float*)(ws + 30720000);     //    640,000
    float* ed     = (float*)(ws + 31360000);     //    640,000
    float* sc     = (float*)(ws + 32000000);     //    160,000
    int*   cnt    = (int*)(ws + 32160000);       //    160,000
    int*   fill   = (int*)(ws + 32320000);       //    160,000 (adjacent to cnt)
    int*   rowptr = (int*)(ws + 32480000);       //    160,016
    int*   csrc   = (int*)(ws + 32640016);       //  2,048,000
    float* wcvt   = (float*)(ws + 34688016);     //    240,000
    float* zbase  = (float*)(ws + 34928016);
    float* bn_accum = zbase;                     //  6*256
    float* pooled   = zbase + 1536;              //  2*8192
    float* bkt      = pooled + 16384;            //  64*256 = 16384 (zeroed)
    float* md       = bkt + 16384;               //  2*128
    float* Tall     = md + 256;                  //  2*64*48 = 6144
    int*   flag     = (int*)(Tall + 6144);       //  1
    int*   bsum     = flag + 4;                  //  NSB

    // ---- weight conversion table ----
    static const int widx[28] = {6,7,8, 10,11,12, 14,15,16, 18,19,20, 23,24,25,
                                 21,26, 22,27, 28, 30,31, 32,33, 34,35, 36,37};
    static const int wn[28]   = {16384,128,128, 16384,128,128, 16384,128,128, 128,128,128,
                                 128,128,128, 48,48, 12,12, 128, 6144,48, 576,12, 288,12, 12,1};
    CvtArgs ca;
    float* wptr[28];
    {
        size_t off = 0;
        for (int i = 0; i < 28; ++i) {
            ca.src[i] = d_in[widx[i]];
            ca.dst[i] = wcvt + off;
            ca.n[i] = wn[i];
            wptr[i] = wcvt + off;
            off += wn[i];
        }
    }
    const float* Wf[3]  = {wptr[0], wptr[3], wptr[6]};
    const float* asf[3] = {wptr[1], wptr[4], wptr[7]};
    const float* adf[3] = {wptr[2], wptr[5], wptr[8]};
    const float* gf[3]  = {wptr[9], wptr[10], wptr[11]};
    const float* bef[3] = {wptr[12], wptr[13], wptr[14]};
    const float *gbi = wptr[15], *bbi = wptr[16], *gf1 = wptr[17], *bf1 = wptr[18];
    const float *attw = wptr[19], *fciw = wptr[20], *fcib = wptr[21];
    const float *fcw = wptr[22], *fcb = wptr[23], *fc1w = wptr[24], *fc1b = wptr[25];
    const float *fc2w = wptr[26], *fc2b = wptr[27];

    detect_k<<<1, 256, 0, stream>>>((const u16*)d_in[0], flag);
    cvt_k<<<28, 256, 0, stream>>>(ca, flag);
    // zero bn_accum + pooled + bkt (contiguous)
    (void)hipMemsetAsync(zbase, 0, (1536 + 16384 + 16384) * sizeof(float), stream);

    for (int b = 0; b < 2; ++b) {
        (void)hipMemsetAsync(cnt, 0, 2 * NN * sizeof(int), stream);  // cnt + fill
        hist_k<<<512, 256, 0, stream>>>(ei[b], cnt);
        scan1_k<<<NSB, 256, 0, stream>>>(cnt, rowptr, bsum);
        scan2_k<<<1, 256, 0, stream>>>(bsum, rowptr);
        scan3_k<<<NSB, 256, 0, stream>>>(rowptr, bsum);
        scatter_k<<<512, 256, 0, stream>>>(ei[b], rowptr, fill, csrc);
        for (int l = 0; l < 3; ++l) {
            float* accp = bn_accum + (b * 3 + l) * 256;
            float* accprev = bn_accum + (b * 3 + l - 1) * 256;  // only read when l>0
            matmul128_k<<<625, 256, 0, stream>>>(l == 0 ? xin[b] : (const void*)A,
                                                 l == 0 ? 0 : 1, flag,
                                                 l == 0 ? bn_accum : accprev,
                                                 l == 0 ? gf[0] : gf[l - 1],
                                                 l == 0 ? bef[0] : bef[l - 1],
                                                 Wf[l], asf[l], adf[l], Hb, es, ed);
            agg_k<<<10000, 256, 0, stream>>>(Hb, es, ed, rowptr, csrc, A, bkt);
            bnreduce_k<<<1, 256, 0, stream>>>(bkt, accp);
        }
        float* acc3 = bn_accum + (b * 3 + 2) * 256;
        pool_score_k<<<10000, 256, 0, stream>>>(A, acc3, gf[2], bef[2], attw, sc);
        pool_stats_k<<<64, 256, 0, stream>>>(sc, batch[b], md + b * 128);
        pool_accum2_k<<<625, 256, 0, stream>>>(A, sc, batch[b], md + b * 128,
                                               acc3, gf[2], bef[2], pooled + b * 8192);
        headA_k<<<64, 256, 0, stream>>>(pooled + b * 8192, fciw, fcib, Tall + b * 3072);
    }
    headB_k<<<1, 256, 0, stream>>>(Tall, gbi, bbi, fcw, fcb, fc1w, fc1b, gf1, bf1,
                                   fc2w, fc2b, d_out, flag);
}